// Round 4
// baseline (799.665 us; speedup 1.0000x reference)
//
#include <hip/hip_runtime.h>
#include <cstdint>
#include <cstddef>

#define MROWS 16384     // B*R = 32*512
#define INDIM 1024
#define DD    256
#define TWO_D 512
#define KC    4096
#define OUTD  1024
#define NZQ   (MROWS * OUTD)   // 16777216

typedef short bfrag __attribute__((ext_vector_type(8)));   // 8 bf16 (4 VGPRs)
typedef float ffrag __attribute__((ext_vector_type(4)));   // 4 fp32 acc

__device__ __forceinline__ ushort f2bf(float f) {          // RNE f32->bf16
    uint u = __float_as_uint(f);
    return (ushort)((u + 0x7FFFu + ((u >> 16) & 1u)) >> 16);
}

// async global->LDS, 16B per lane, dest = wave-uniform base + lane*16
#define GLD16(dst, src)                                                        \
    __builtin_amdgcn_global_load_lds(                                          \
        (const __attribute__((address_space(1))) unsigned int*)(src),          \
        (__attribute__((address_space(3))) unsigned int*)(dst), 16, 0, 0)

// ---------------------------------------------------------------------------
// K1: h = z @ W_qa + b_qa  (fp32, strict sequential-k accumulation -> matches
// np sgemm bits; LOAD-BEARING: per-element FMA chain must stay k-ascending).
// R4: 8x16 microtile, 128-thread blocks. LDS-read traffic 1.0 -> 0.75 B/FMA
// (R3 counters: LDS pipe was ~73% utilized = binding; VALU 61%). 4 blocks/CU
// (was 2) -> staggered, cheaper 2-wave barriers. Staging via global_load_lds
// into dbuf LDS, stage(t+1) before compute(t), one barrier/step (R3-verified).
// A [row][16k] with XOR-swizzled k-quads (src pre-swizzle (l&3)^((l>>4)&3),
// read q^(ty&3)); B [16][128] linear (2-way aliasing only = free).
// FMA order t->q->c = k strictly ascending -> h bit-exact vs round-0.
// Grid (128, 4), block 128. Also emits h_bf16.
// ---------------------------------------------------------------------------
__global__ __launch_bounds__(128, 2) void k_gemm1(const float* __restrict__ z,
                                                  const float* __restrict__ Wqa,
                                                  const float* __restrict__ bqa,
                                                  float* __restrict__ h,
                                                  ushort* __restrict__ hbf) {
    __shared__ float As[2][128][16];   // 16 KB  [buf][row][k] (k-quads swizzled)
    __shared__ float Bs[2][16][128];   // 16 KB  [buf][k][col] linear
    const int tid = threadIdx.x;       // 0..127
    const int l = tid & 63, w = tid >> 6;
    const int tx = tid & 7, ty = tid >> 3;   // tx 0..7 (cols), ty 0..15 (rows)
    const int rb = blockIdx.x * 128;
    const int cb = blockIdx.y * 128;

    float acc[8][16] = {};

    // --- staging source pointers (per lane) ---
    // A instr j (j=0..3): wave w rows 64w+16j..+15; lane l -> row +(l>>2),
    // slot-quad l&3 holds source k-quad (l&3)^((l>>4)&3) (= (l&3)^((row>>2)&3)).
    const int sA = 4 * ((l & 3) ^ ((l >> 4) & 3));
    const float* aA = z + (size_t)(rb + 64 * w + (l >> 2)) * INDIM + sA;
    // B instr j (j=0..3): wave w k-rows 8w+2j..+1; lane l -> k-row +(l>>5),
    // cols 4*(l&31).
    const float* bB = Wqa + (size_t)(8 * w + (l >> 5)) * TWO_D + cb + (l & 31) * 4;

#define STAGE(buf, k0)                                                         \
    do {                                                                       \
        GLD16(&As[buf][64 * w][0],      aA + (k0));                            \
        GLD16(&As[buf][64 * w + 16][0], aA + (size_t)16 * INDIM + (k0));       \
        GLD16(&As[buf][64 * w + 32][0], aA + (size_t)32 * INDIM + (k0));       \
        GLD16(&As[buf][64 * w + 48][0], aA + (size_t)48 * INDIM + (k0));       \
        GLD16(&Bs[buf][8 * w][0],       bB + (size_t)((k0) + 0) * TWO_D);      \
        GLD16(&Bs[buf][8 * w + 2][0],   bB + (size_t)((k0) + 2) * TWO_D);      \
        GLD16(&Bs[buf][8 * w + 4][0],   bB + (size_t)((k0) + 4) * TWO_D);      \
        GLD16(&Bs[buf][8 * w + 6][0],   bB + (size_t)((k0) + 6) * TWO_D);      \
    } while (0)

    STAGE(0, 0);
    __syncthreads();

    const int xk = ty & 3;    // read-side XOR key = (row>>2)&3 for all 8 rows
    for (int t = 0; t < 64; ++t) {
        const int cur = t & 1;
        if (t < 63) STAGE(cur ^ 1, (t + 1) * 16);   // async, drained by barrier
        #pragma unroll
        for (int q = 0; q < 4; ++q) {               // k-quad
            float fav[8][4];
            #pragma unroll
            for (int i = 0; i < 4; ++i) {
                *reinterpret_cast<float4*>(&fav[i][0]) =
                    *reinterpret_cast<const float4*>(&As[cur][ty * 4 + i][(q ^ xk) * 4]);
                *reinterpret_cast<float4*>(&fav[4 + i][0]) =
                    *reinterpret_cast<const float4*>(&As[cur][64 + ty * 4 + i][(q ^ xk) * 4]);
            }
            #pragma unroll
            for (int c = 0; c < 4; ++c) {           // kk = 4q+c, ascending
                const int kk = q * 4 + c;
                float4 b0 = *reinterpret_cast<const float4*>(&Bs[cur][kk][tx * 8]);
                float4 b1 = *reinterpret_cast<const float4*>(&Bs[cur][kk][tx * 8 + 4]);
                float4 b2 = *reinterpret_cast<const float4*>(&Bs[cur][kk][64 + tx * 8]);
                float4 b3 = *reinterpret_cast<const float4*>(&Bs[cur][kk][64 + tx * 8 + 4]);
                float bv[16] = {b0.x, b0.y, b0.z, b0.w, b1.x, b1.y, b1.z, b1.w,
                                b2.x, b2.y, b2.z, b2.w, b3.x, b3.y, b3.z, b3.w};
                #pragma unroll
                for (int i = 0; i < 8; ++i)
                    #pragma unroll
                    for (int j = 0; j < 16; ++j)
                        acc[i][j] = fmaf(fav[i][c], bv[j], acc[i][j]);
            }
        }
        __syncthreads();   // drains this wave's STAGE vmcnt + orders LDS reuse
    }
#undef STAGE

    #pragma unroll
    for (int i = 0; i < 8; ++i) {
        const int row = rb + ((i < 4) ? (ty * 4 + i) : (64 + ty * 4 + i - 4));
        #pragma unroll
        for (int jh = 0; jh < 2; ++jh) {
            const int col = cb + jh * 64 + tx * 8;
            float4 q0 = *reinterpret_cast<const float4*>(&bqa[col]);
            float4 q1 = *reinterpret_cast<const float4*>(&bqa[col + 4]);
            float v[8] = {acc[i][jh * 8 + 0] + q0.x, acc[i][jh * 8 + 1] + q0.y,
                          acc[i][jh * 8 + 2] + q0.z, acc[i][jh * 8 + 3] + q0.w,
                          acc[i][jh * 8 + 4] + q1.x, acc[i][jh * 8 + 5] + q1.y,
                          acc[i][jh * 8 + 6] + q1.z, acc[i][jh * 8 + 7] + q1.w};
            *reinterpret_cast<float4*>(&h[(size_t)row * TWO_D + col]) =
                *reinterpret_cast<const float4*>(&v[0]);
            *reinterpret_cast<float4*>(&h[(size_t)row * TWO_D + col + 4]) =
                *reinterpret_cast<const float4*>(&v[4]);
            ushort u[8] = {f2bf(v[0]), f2bf(v[1]), f2bf(v[2]), f2bf(v[3]),
                           f2bf(v[4]), f2bf(v[5]), f2bf(v[6]), f2bf(v[7])};
            *reinterpret_cast<uint4*>(&hbf[(size_t)row * TWO_D + col]) =
                *reinterpret_cast<const uint4*>(&u[0]);
        }
    }
}

// ---------------------------------------------------------------------------
// K2: row norms R[half][row] (fp32; few-ulp accuracy suffices — d = R-2M is
// exact on the quantum grid, so a uniform R shift preserves argmin & ties).
// Grid 8192, block 256.
// ---------------------------------------------------------------------------
__global__ __launch_bounds__(256) void k_rnorm(const float* __restrict__ h,
                                               float* __restrict__ Rn) {
    const int wave = threadIdx.x >> 6;
    const int lane = threadIdx.x & 63;
    const int item = blockIdx.x * 4 + wave;
    const int row  = item & (MROWS - 1);
    const int half = item >> 14;
    float4 v = *reinterpret_cast<const float4*>(&h[(size_t)row * TWO_D + half * DD + lane * 4]);
    float s = v.x * v.x + v.y * v.y + v.z * v.z + v.w * v.w;
    #pragma unroll
    for (int off = 32; off; off >>= 1) s += __shfl_down(s, off, 64);
    if (lane == 0) Rn[half * MROWS + row] = s;
}

// ---------------------------------------------------------------------------
// K3: fused bf16 converts. Blocks [0,2048): emb1|emb2 -> ebf.
// Blocks [2048,2560): W_pq [512][1024] -> transposed bf16 [1024][512].
// ---------------------------------------------------------------------------
__global__ __launch_bounds__(256) void k_cvt(const float* __restrict__ e1,
                                             const float* __restrict__ e2,
                                             const float* __restrict__ Wpq,
                                             ushort* __restrict__ ebf,
                                             ushort* __restrict__ wbfT) {
    const int b = blockIdx.x;
    if (b < 2048) {
        const size_t v = ((size_t)b * 256 + threadIdx.x) * 4;
        const size_t half = (size_t)KC * DD;
        const float* src = (v < half) ? (e1 + v) : (e2 + (v - half));
        float4 f = *reinterpret_cast<const float4*>(src);
        ebf[v + 0] = f2bf(f.x); ebf[v + 1] = f2bf(f.y);
        ebf[v + 2] = f2bf(f.z); ebf[v + 3] = f2bf(f.w);
    } else {
        const int e = ((b - 2048) * 256 + threadIdx.x) * 4;   // 0..524284
        const int k = e >> 10, c = e & 1023;
        float4 f = *reinterpret_cast<const float4*>(&Wpq[e]);
        wbfT[(size_t)(c + 0) * TWO_D + k] = f2bf(f.x);
        wbfT[(size_t)(c + 1) * TWO_D + k] = f2bf(f.y);
        wbfT[(size_t)(c + 2) * TWO_D + k] = f2bf(f.z);
        wbfT[(size_t)(c + 3) * TWO_D + k] = f2bf(f.w);
    }
}

// ---------------------------------------------------------------------------
// K4: MFMA score pass (selection only). C[row,code] = <h_bf, e_bf>, bf16
// 16x16x32 MFMA, 128x128 block tile, wave = 64x64 (4x4 frags), K=256 in 8
// chunks of 32. XOR-swizzled LDS -> conflict-free frag reads. Per-wave
// per-row top-2 packed keys -> cand[cb][seg(64)][row][2]. Grid (128,32,2).
// ---------------------------------------------------------------------------
__global__ __launch_bounds__(256) void k_score_mfma(const ushort* __restrict__ hbf,
                                                    const ushort* __restrict__ ebf,
                                                    uint* __restrict__ cand) {
    __shared__ ushort Ab[4][128][8];   // 8 KB
    __shared__ ushort Bb[4][128][8];   // 8 KB
    const int tid = threadIdx.x;
    const int l = tid & 63, w = tid >> 6;
    const int rb    = blockIdx.x * 128;
    const int cbcol = blockIdx.y * 128;
    const int cbk   = blockIdx.z;
    const ushort* hb = hbf + cbk * DD;                 // row stride TWO_D
    const ushort* eb = ebf + (size_t)cbk * KC * DD;    // row stride DD

    const int ry = (w & 1) * 64;
    const int cy = (w >> 1) * 64;

    ffrag acc[4][4];
    #pragma unroll
    for (int i = 0; i < 4; ++i)
        #pragma unroll
        for (int j = 0; j < 4; ++j)
            acc[i][j] = (ffrag){0.f, 0.f, 0.f, 0.f};

    for (int k0 = 0; k0 < DD; k0 += 32) {
        #pragma unroll
        for (int it = 0; it < 2; ++it) {
            const int r = it * 64 + l;
            uint4 va = *reinterpret_cast<const uint4*>(hb + (size_t)(rb + r) * TWO_D + k0 + w * 8);
            *reinterpret_cast<uint4*>(&Ab[w ^ ((r >> 1) & 3)][r][0]) = va;
            uint4 vb = *reinterpret_cast<const uint4*>(eb + (size_t)(cbcol + r) * DD + k0 + w * 8);
            *reinterpret_cast<uint4*>(&Bb[w ^ ((r >> 1) & 3)][r][0]) = vb;
        }
        __syncthreads();
        const int q = l >> 4, li = l & 15;
        bfrag afr[4], bfr[4];
        #pragma unroll
        for (int rf = 0; rf < 4; ++rf) {
            const int r = ry + rf * 16 + li;
            afr[rf] = *reinterpret_cast<const bfrag*>(&Ab[q ^ ((r >> 1) & 3)][r][0]);
        }
        #pragma unroll
        for (int cf = 0; cf < 4; ++cf) {
            const int c = cy + cf * 16 + li;
            bfr[cf] = *reinterpret_cast<const bfrag*>(&Bb[q ^ ((c >> 1) & 3)][c][0]);
        }
        #pragma unroll
        for (int rf = 0; rf < 4; ++rf)
            #pragma unroll
            for (int cf = 0; cf < 4; ++cf)
                acc[rf][cf] = __builtin_amdgcn_mfma_f32_16x16x32_bf16(afr[rf], bfr[cf],
                                                                      acc[rf][cf], 0, 0, 0);
        __syncthreads();
    }

    const int q = l >> 4, li = l & 15;
    const int seg = blockIdx.y * 2 + (w >> 1);
    #pragma unroll
    for (int rf = 0; rf < 4; ++rf) {
        #pragma unroll
        for (int reg = 0; reg < 4; ++reg) {
            const int row = rb + ry + rf * 16 + q * 4 + reg;
            uint k1 = 0, k2 = 0;
            #pragma unroll
            for (int cf = 0; cf < 4; ++cf) {
                float v = acc[rf][cf][reg];
                const int code = cbcol + cy + cf * 16 + li;
                uint u = __float_as_uint(v);
                u ^= (0x80000000u | (uint)((int)u >> 31));      // order-preserving flip
                const uint key = (u & 0xFFFFF000u) | (uint)code;
                if (key > k1) { k2 = k1; k1 = key; }
                else if (key > k2) { k2 = key; }
            }
            #pragma unroll
            for (int m = 1; m < 16; m <<= 1) {
                uint o1 = __shfl_xor((int)k1, m, 64);
                uint o2 = __shfl_xor((int)k2, m, 64);
                uint n1 = k1 > o1 ? k1 : o1;
                uint lo = k1 > o1 ? o1 : k1;
                uint hi2 = k2 > o2 ? k2 : o2;
                k2 = lo > hi2 ? lo : hi2;
                k1 = n1;
            }
            if (li == 0) {
                const size_t base = ((size_t)(cbk * 64 + seg) * MROWS + row) * 2;
                cand[base] = k1; cand[base + 1] = k2;
            }
        }
    }
}

// ---------------------------------------------------------------------------
// K5: reduce. Per (row, cb): scan 64 segs x top-2 keys, take top-8, exact
// fp32 sequential dot (np-sgemm bits), d = fp32(Rn - 2M), min(d, idx).
// One wave per row-cb pair. Grid 8192, block 256.
// ---------------------------------------------------------------------------
__global__ __launch_bounds__(256) void k_reduce(const uint* __restrict__ cand,
                                                const float* __restrict__ h,
                                                const float* __restrict__ emb1,
                                                const float* __restrict__ emb2,
                                                const float* __restrict__ Rn,
                                                float* __restrict__ dout_idx) {
    const int tid = threadIdx.x;
    const int l = tid & 63, w = tid >> 6;
    const int item = blockIdx.x * 4 + w;
    const int cb  = item >> 14;
    const int row = item & (MROWS - 1);

    const size_t base = ((size_t)(cb * 64 + l) * MROWS + row) * 2;
    uint k1 = cand[base], k2 = cand[base + 1];

    uint mykey = 0;
    #pragma unroll
    for (int t = 0; t < 8; ++t) {
        uint m = k1 > k2 ? k1 : k2;
        #pragma unroll
        for (int off = 1; off < 64; off <<= 1) {
            uint o = __shfl_xor((int)m, off, 64);
            m = m > o ? m : o;
        }
        if (k1 == m) k1 = 0; else if (k2 == m) k2 = 0;
        if (l == t) mykey = m;
    }

    float dd = INFINITY; int code = 0x7fffffff;
    if (l < 8) {
        code = (int)(mykey & 0xFFFu);
        const float* hr = h + (size_t)row * TWO_D + cb * DD;
        const float* er = (cb ? emb2 : emb1) + (size_t)code * DD;
        float M = 0.f;
        for (int d = 0; d < DD; ++d) M = fmaf(hr[d], er[d], M);  // sequential chain
        dd = Rn[cb * MROWS + row] - 2.0f * M;
    }
    #pragma unroll
    for (int off = 1; off < 8; off <<= 1) {
        float od = __shfl_xor(dd, off, 64);
        int   oc = __shfl_xor(code, off, 64);
        if (od < dd || (od == dd && oc < code)) { dd = od; code = oc; }
    }
    if (l == 0) dout_idx[cb * MROWS + row] = (float)code;
}

// ---------------------------------------------------------------------------
// K6: per-row loss = (sum of both halves' squared diffs) * 0.625/256.
// Grid 16384, block 256.
// ---------------------------------------------------------------------------
__global__ __launch_bounds__(256) void k_loss(const float* __restrict__ h,
                                              const float* __restrict__ emb1,
                                              const float* __restrict__ emb2,
                                              const float* __restrict__ idxf,
                                              float* __restrict__ dout_loss) {
    __shared__ float red[4];
    const int r = blockIdx.x;
    const int d = threadIdx.x;
    const int ia = (int)idxf[r];
    const int ib = (int)idxf[MROWS + r];
    float e1 = emb1[(size_t)ia * DD + d];
    float e2 = emb2[(size_t)ib * DD + d];
    float h1 = h[(size_t)r * TWO_D + d];
    float h2 = h[(size_t)r * TWO_D + DD + d];
    float d1 = e1 - h1, d2 = e2 - h2;
    float p = d1 * d1 + d2 * d2;
    #pragma unroll
    for (int off = 32; off; off >>= 1) p += __shfl_down(p, off, 64);
    const int lane = d & 63, wv = d >> 6;
    if (lane == 0) red[wv] = p;
    __syncthreads();
    if (d == 0) {
        float s = red[0] + red[1] + red[2] + red[3];
        dout_loss[r] = s * (0.625f / 256.0f);
    }
}

// ---------------------------------------------------------------------------
// K7: out = gather(e_bf, idx) @ W_pq_bf + b_pq via MFMA (bf16 in, fp32 out).
// Grid (128, 8), block 256.
// ---------------------------------------------------------------------------
__global__ __launch_bounds__(256) void k_gemm2m(const ushort* __restrict__ ebf,
                                                const ushort* __restrict__ wbfT,
                                                const float* __restrict__ idxf,
                                                const float* __restrict__ bpq,
                                                float* __restrict__ out) {
    __shared__ ushort Ab[4][128][8];
    __shared__ ushort Bb[4][128][8];
    const int tid = threadIdx.x;
    const int l = tid & 63, w = tid >> 6;
    const int rb    = blockIdx.x * 128;
    const int cbcol = blockIdx.y * 128;
    const int ry = (w & 1) * 64;
    const int cy = (w >> 1) * 64;
    const ushort* e1 = ebf;
    const ushort* e2 = ebf + (size_t)KC * DD;

    int ia[2], ib[2];
    ia[0] = (int)idxf[rb + l];            ia[1] = (int)idxf[rb + 64 + l];
    ib[0] = (int)idxf[MROWS + rb + l];    ib[1] = (int)idxf[MROWS + rb + 64 + l];

    ffrag acc[4][4];
    #pragma unroll
    for (int i = 0; i < 4; ++i)
        #pragma unroll
        for (int j = 0; j < 4; ++j)
            acc[i][j] = (ffrag){0.f, 0.f, 0.f, 0.f};

    for (int k0 = 0; k0 < TWO_D; k0 += 32) {
        const int cbs = k0 >> 8;
        const int kk  = (k0 & 255) + w * 8;
        #pragma unroll
        for (int it = 0; it < 2; ++it) {
            const int r = it * 64 + l;
            const int idx = cbs ? ib[it] : ia[it];
            const ushort* src = (cbs ? e2 : e1) + (size_t)idx * DD + kk;
            *reinterpret_cast<uint4*>(&Ab[w ^ ((r >> 1) & 3)][r][0]) =
                *reinterpret_cast<const uint4*>(src);
            const ushort* bs = wbfT + (size_t)(cbcol + r) * TWO_D + k0 + w * 8;
            *reinterpret_cast<uint4*>(&Bb[w ^ ((r >> 1) & 3)][r][0]) =
                *reinterpret_cast<const uint4*>(bs);
        }
        __syncthreads();
        const int q = l >> 4, li = l & 15;
        bfrag afr[4], bfr[4];
        #pragma unroll
        for (int rf = 0; rf < 4; ++rf) {
            const int r = ry + rf * 16 + li;
            afr[rf] = *reinterpret_cast<const bfrag*>(&Ab[q ^ ((r >> 1) & 3)][r][0]);
        }
        #pragma unroll
        for (int cf = 0; cf < 4; ++cf) {
            const int c = cy + cf * 16 + li;
            bfr[cf] = *reinterpret_cast<const bfrag*>(&Bb[q ^ ((c >> 1) & 3)][c][0]);
        }
        #pragma unroll
        for (int rf = 0; rf < 4; ++rf)
            #pragma unroll
            for (int cf = 0; cf < 4; ++cf)
                acc[rf][cf] = __builtin_amdgcn_mfma_f32_16x16x32_bf16(afr[rf], bfr[cf],
                                                                      acc[rf][cf], 0, 0, 0);
        __syncthreads();
    }

    const int q = l >> 4, li = l & 15;
    #pragma unroll
    for (int rf = 0; rf < 4; ++rf) {
        #pragma unroll
        for (int reg = 0; reg < 4; ++reg) {
            const int row = rb + ry + rf * 16 + q * 4 + reg;
            #pragma unroll
            for (int cf = 0; cf < 4; ++cf) {
                const int col = cbcol + cy + cf * 16 + li;
                out[(size_t)row * OUTD + col] = acc[rf][cf][reg] + bpq[col];
            }
        }
    }
}

// ---------------------------------------------------------------------------
extern "C" void kernel_launch(void* const* d_in, const int* in_sizes, int n_in,
                              void* d_out, int out_size, void* d_ws, size_t ws_size,
                              hipStream_t stream) {
    const float* z    = (const float*)d_in[0];
    const float* Wqa  = (const float*)d_in[1];
    const float* bqa  = (const float*)d_in[2];
    const float* emb1 = (const float*)d_in[3];
    const float* emb2 = (const float*)d_in[4];
    const float* Wpq  = (const float*)d_in[5];
    const float* bpq  = (const float*)d_in[6];
    float* out = (float*)d_out;

    const size_t H = (size_t)MROWS * TWO_D;        // 8,388,608
    float*  hbuf = (float*)d_ws;                   // [H]            33.55 MB
    float*  Rn   = hbuf + H;                       // [2*MROWS]       0.13 MB
    ushort* hbf  = (ushort*)(Rn + 2 * MROWS);      // [H]            16.78 MB
    ushort* ebf  = hbf + H;                        // [2*KC*DD]       4.19 MB
    ushort* wbfT = ebf + 2 * (size_t)KC * DD;      // [OUTD*TWO_D]    1.05 MB
    uint*   cand = (uint*)(wbfT + (size_t)OUTD * TWO_D); // [2*64*MROWS*2] 16.78 MB

    float* dout_idx  = out + NZQ;
    float* dout_loss = out + NZQ + 2 * MROWS;

    k_gemm1<<<dim3(128, 4), 128, 0, stream>>>(z, Wqa, bqa, hbuf, hbf);
    k_rnorm<<<8192, 256, 0, stream>>>(hbuf, Rn);
    k_cvt<<<2560, 256, 0, stream>>>(emb1, emb2, Wpq, ebf, wbfT);
    k_score_mfma<<<dim3(128, 32, 2), 256, 0, stream>>>(hbf, ebf, cand);
    k_reduce<<<8192, 256, 0, stream>>>(cand, hbuf, emb1, emb2, Rn, dout_idx);
    k_loss<<<16384, 256, 0, stream>>>(hbuf, emb1, emb2, dout_idx, dout_loss);
    k_gemm2m<<<dim3(128, 8), 256, 0, stream>>>(ebf, wbfT, dout_idx, bpq, out);
}

// Round 5
// 618.109 us; speedup vs baseline: 1.2937x; 1.2937x over previous
//
#include <hip/hip_runtime.h>
#include <cstdint>
#include <cstddef>

#define MROWS 16384     // B*R = 32*512
#define INDIM 1024
#define DD    256
#define TWO_D 512
#define KC    4096
#define OUTD  1024
#define NZQ   (MROWS * OUTD)   // 16777216

typedef short bfrag __attribute__((ext_vector_type(8)));   // 8 bf16 (4 VGPRs)
typedef float ffrag __attribute__((ext_vector_type(4)));   // 4 fp32 acc

__device__ __forceinline__ ushort f2bf(float f) {          // RNE f32->bf16
    uint u = __float_as_uint(f);
    return (ushort)((u + 0x7FFFu + ((u >> 16) & 1u)) >> 16);
}

// async global->LDS, 16B per lane, dest = wave-uniform base + lane*16
#define GLD16(dst, src)                                                        \
    __builtin_amdgcn_global_load_lds(                                          \
        (const __attribute__((address_space(1))) unsigned int*)(src),          \
        (__attribute__((address_space(3))) unsigned int*)(dst), 16, 0, 0)

// ---------------------------------------------------------------------------
// K1: h = z @ W_qa + b_qa  (fp32, strict sequential-k accumulation -> matches
// np sgemm bits; LOAD-BEARING: per-element FMA chain must stay k-ascending).
// R3 structure (verified 225us): 128x128 tile, 8x8 microtile, 256 threads.
// Staging via global_load_lds into dbuf LDS; stage(t+1) before compute(t);
// one barrier/step. A [row][16k] with XOR-swizzled k-quads (src pre-swizzle
// (l&3)^((l>>4)&3), read q^(ty&3)); B [16][128] linear (2-way only = free).
// R4 lesson: 8x16 micro forces 1 wave/SIMD (grid-limited) -> 363us. 8x8 is
// the occupancy-feasible optimum. Grid (128, 4), block 256.
// ---------------------------------------------------------------------------
__global__ __launch_bounds__(256) void k_gemm1(const float* __restrict__ z,
                                               const float* __restrict__ Wqa,
                                               const float* __restrict__ bqa,
                                               float* __restrict__ h,
                                               ushort* __restrict__ hbf) {
    __shared__ float As[2][128][16];   // 16 KB  [buf][row][k] (k-quads swizzled)
    __shared__ float Bs[2][16][128];   // 16 KB  [buf][k][col] linear
    const int tid = threadIdx.x;
    const int l = tid & 63, w = tid >> 6;
    const int tx = tid & 15, ty = tid >> 4;
    const int rb = blockIdx.x * 128;
    const int cb = blockIdx.y * 128;

    float acc[8][8] = {};

    // --- staging source pointers (per lane) ---
    const int sA = 4 * ((l & 3) ^ ((l >> 4) & 3));
    const float* aA0 = z + (size_t)(rb + 32 * w + (l >> 2)) * INDIM + sA;
    const float* aA1 = aA0 + (size_t)16 * INDIM;
    const float* bB0 = Wqa + (size_t)(4 * w + (l >> 5)) * TWO_D + cb + (l & 31) * 4;
    const float* bB1 = bB0 + (size_t)2 * TWO_D;

#define STAGE(buf, k0)                                                         \
    do {                                                                       \
        GLD16(&As[buf][32 * w][0],      aA0 + (k0));                           \
        GLD16(&As[buf][32 * w + 16][0], aA1 + (k0));                           \
        GLD16(&Bs[buf][4 * w][0],       bB0 + (size_t)(k0) * TWO_D);           \
        GLD16(&Bs[buf][4 * w + 2][0],   bB1 + (size_t)(k0) * TWO_D);           \
    } while (0)

    STAGE(0, 0);
    __syncthreads();

    const int xk = ty & 3;    // read-side XOR key = (row>>2)&3 for all 8 rows
    for (int t = 0; t < 64; ++t) {
        const int cur = t & 1;
        if (t < 63) STAGE(cur ^ 1, (t + 1) * 16);   // async, lands by barrier
        #pragma unroll
        for (int q = 0; q < 4; ++q) {               // k-quad
            float fa[8][4];
            #pragma unroll
            for (int i = 0; i < 4; ++i) {
                *reinterpret_cast<float4*>(&fa[i][0]) =
                    *reinterpret_cast<const float4*>(&As[cur][ty * 4 + i][(q ^ xk) * 4]);
                *reinterpret_cast<float4*>(&fa[4 + i][0]) =
                    *reinterpret_cast<const float4*>(&As[cur][64 + ty * 4 + i][(q ^ xk) * 4]);
            }
            #pragma unroll
            for (int c = 0; c < 4; ++c) {           // kk = 4q+c, ascending
                const int kk = q * 4 + c;
                float4 b0 = *reinterpret_cast<const float4*>(&Bs[cur][kk][tx * 4]);
                float4 b1 = *reinterpret_cast<const float4*>(&Bs[cur][kk][64 + tx * 4]);
                float bv[8] = {b0.x, b0.y, b0.z, b0.w, b1.x, b1.y, b1.z, b1.w};
                #pragma unroll
                for (int i = 0; i < 8; ++i)
                    #pragma unroll
                    for (int j = 0; j < 8; ++j)
                        acc[i][j] = fmaf(fa[i][c], bv[j], acc[i][j]);
            }
        }
        __syncthreads();   // drains this wave's STAGE vmcnt + orders LDS reuse
    }
#undef STAGE

    #pragma unroll
    for (int i = 0; i < 8; ++i) {
        const int row = rb + ((i < 4) ? (ty * 4 + i) : (64 + ty * 4 + i - 4));
        #pragma unroll
        for (int jh = 0; jh < 2; ++jh) {
            const int col = cb + jh * 64 + tx * 4;
            float v0 = acc[i][jh * 4 + 0] + bqa[col + 0];
            float v1 = acc[i][jh * 4 + 1] + bqa[col + 1];
            float v2 = acc[i][jh * 4 + 2] + bqa[col + 2];
            float v3 = acc[i][jh * 4 + 3] + bqa[col + 3];
            float4 vf = {v0, v1, v2, v3};
            *reinterpret_cast<float4*>(&h[(size_t)row * TWO_D + col]) = vf;
            ushort u[4] = {f2bf(v0), f2bf(v1), f2bf(v2), f2bf(v3)};
            *reinterpret_cast<uint2*>(&hbf[(size_t)row * TWO_D + col]) =
                *reinterpret_cast<uint2*>(u);
        }
    }
}

// ---------------------------------------------------------------------------
// K2: row norms R[half][row] (fp32; few-ulp accuracy suffices — d = R-2M is
// exact on the quantum grid, so a uniform R shift preserves argmin & ties).
// Grid 8192, block 256.
// ---------------------------------------------------------------------------
__global__ __launch_bounds__(256) void k_rnorm(const float* __restrict__ h,
                                               float* __restrict__ Rn) {
    const int wave = threadIdx.x >> 6;
    const int lane = threadIdx.x & 63;
    const int item = blockIdx.x * 4 + wave;
    const int row  = item & (MROWS - 1);
    const int half = item >> 14;
    float4 v = *reinterpret_cast<const float4*>(&h[(size_t)row * TWO_D + half * DD + lane * 4]);
    float s = v.x * v.x + v.y * v.y + v.z * v.z + v.w * v.w;
    #pragma unroll
    for (int off = 32; off; off >>= 1) s += __shfl_down(s, off, 64);
    if (lane == 0) Rn[half * MROWS + row] = s;
}

// ---------------------------------------------------------------------------
// K3: fused bf16 converts. Blocks [0,2048): emb1|emb2 -> ebf.
// Blocks [2048,2560): W_pq [512][1024] -> transposed bf16 [1024][512].
// ---------------------------------------------------------------------------
__global__ __launch_bounds__(256) void k_cvt(const float* __restrict__ e1,
                                             const float* __restrict__ e2,
                                             const float* __restrict__ Wpq,
                                             ushort* __restrict__ ebf,
                                             ushort* __restrict__ wbfT) {
    const int b = blockIdx.x;
    if (b < 2048) {
        const size_t v = ((size_t)b * 256 + threadIdx.x) * 4;
        const size_t half = (size_t)KC * DD;
        const float* src = (v < half) ? (e1 + v) : (e2 + (v - half));
        float4 f = *reinterpret_cast<const float4*>(src);
        ebf[v + 0] = f2bf(f.x); ebf[v + 1] = f2bf(f.y);
        ebf[v + 2] = f2bf(f.z); ebf[v + 3] = f2bf(f.w);
    } else {
        const int e = ((b - 2048) * 256 + threadIdx.x) * 4;   // 0..524284
        const int k = e >> 10, c = e & 1023;
        float4 f = *reinterpret_cast<const float4*>(&Wpq[e]);
        wbfT[(size_t)(c + 0) * TWO_D + k] = f2bf(f.x);
        wbfT[(size_t)(c + 1) * TWO_D + k] = f2bf(f.y);
        wbfT[(size_t)(c + 2) * TWO_D + k] = f2bf(f.z);
        wbfT[(size_t)(c + 3) * TWO_D + k] = f2bf(f.w);
    }
}

// ---------------------------------------------------------------------------
// K4: MFMA score pass (selection only). C[row,code] = <h_bf, e_bf>, bf16
// 16x16x32 MFMA, 128x128 block tile, wave = 64x64 (4x4 frags), K=256 in 8
// chunks of 32.
// R5: staging via global_load_lds (was reg-staged: 2 loads + 2 ds_writes per
// thread per chunk) into double-buffered LDS; stage(c+1) before compute(c),
// one barrier/chunk (m97 structure). Store-side XOR swizzle moved into the
// per-lane SOURCE address (m173): Ab[s][r] holds octet s ^ ((r>>1)&3) — same
// content as before, read path unchanged (conflict-free).
// Per-wave per-row top-2 packed keys -> cand. Grid (128,32,2), block 256.
// ---------------------------------------------------------------------------
__global__ __launch_bounds__(256) void k_score_mfma(const ushort* __restrict__ hbf,
                                                    const ushort* __restrict__ ebf,
                                                    uint* __restrict__ cand) {
    __shared__ ushort Ab[2][4][128][8];   // 16 KB
    __shared__ ushort Bb[2][4][128][8];   // 16 KB
    const int tid = threadIdx.x;
    const int l = tid & 63, w = tid >> 6;
    const int rb    = blockIdx.x * 128;
    const int cbcol = blockIdx.y * 128;
    const int cbk   = blockIdx.z;
    const ushort* hb = hbf + cbk * DD;                 // row stride TWO_D
    const ushort* eb = ebf + (size_t)cbk * KC * DD;    // row stride DD

    const int ry = (w & 1) * 64;
    const int cy = (w >> 1) * 64;

    // staging: wave w writes subtile w linearly; lane l sources the octet
    // w ^ ((l>>1)&3) of its row -> Ab[s][r] = octet s ^ ((r>>1)&3) of row r
    // (identical content to old swizzled ds_write layout).
    const int koct = (w ^ ((l >> 1) & 3)) * 8;
    const ushort* aS0 = hb + (size_t)(rb + l) * TWO_D + koct;
    const ushort* aS1 = hb + (size_t)(rb + 64 + l) * TWO_D + koct;
    const ushort* bS0 = eb + (size_t)(cbcol + l) * DD + koct;
    const ushort* bS1 = eb + (size_t)(cbcol + 64 + l) * DD + koct;

#define SSTAGE(buf, k0)                                                        \
    do {                                                                       \
        GLD16(&Ab[buf][w][0][0],  aS0 + (k0));                                 \
        GLD16(&Ab[buf][w][64][0], aS1 + (k0));                                 \
        GLD16(&Bb[buf][w][0][0],  bS0 + (k0));                                 \
        GLD16(&Bb[buf][w][64][0], bS1 + (k0));                                 \
    } while (0)

    ffrag acc[4][4];
    #pragma unroll
    for (int i = 0; i < 4; ++i)
        #pragma unroll
        for (int j = 0; j < 4; ++j)
            acc[i][j] = (ffrag){0.f, 0.f, 0.f, 0.f};

    SSTAGE(0, 0);
    __syncthreads();

    const int q = l >> 4, li = l & 15;
    for (int c = 0; c < 8; ++c) {
        const int cur = c & 1;
        if (c < 7) SSTAGE(cur ^ 1, (c + 1) * 32);   // async, drained by barrier
        bfrag afr[4], bfr[4];
        #pragma unroll
        for (int rf = 0; rf < 4; ++rf) {
            const int r = ry + rf * 16 + li;
            afr[rf] = *reinterpret_cast<const bfrag*>(&Ab[cur][q ^ ((r >> 1) & 3)][r][0]);
        }
        #pragma unroll
        for (int cf = 0; cf < 4; ++cf) {
            const int cc = cy + cf * 16 + li;
            bfr[cf] = *reinterpret_cast<const bfrag*>(&Bb[cur][q ^ ((cc >> 1) & 3)][cc][0]);
        }
        #pragma unroll
        for (int rf = 0; rf < 4; ++rf)
            #pragma unroll
            for (int cf = 0; cf < 4; ++cf)
                acc[rf][cf] = __builtin_amdgcn_mfma_f32_16x16x32_bf16(afr[rf], bfr[cf],
                                                                      acc[rf][cf], 0, 0, 0);
        __syncthreads();
    }
#undef SSTAGE

    const int seg = blockIdx.y * 2 + (w >> 1);
    #pragma unroll
    for (int rf = 0; rf < 4; ++rf) {
        #pragma unroll
        for (int reg = 0; reg < 4; ++reg) {
            const int row = rb + ry + rf * 16 + q * 4 + reg;
            uint k1 = 0, k2 = 0;
            #pragma unroll
            for (int cf = 0; cf < 4; ++cf) {
                float v = acc[rf][cf][reg];
                const int code = cbcol + cy + cf * 16 + li;
                uint u = __float_as_uint(v);
                u ^= (0x80000000u | (uint)((int)u >> 31));      // order-preserving flip
                const uint key = (u & 0xFFFFF000u) | (uint)code;
                if (key > k1) { k2 = k1; k1 = key; }
                else if (key > k2) { k2 = key; }
            }
            #pragma unroll
            for (int m = 1; m < 16; m <<= 1) {
                uint o1 = __shfl_xor((int)k1, m, 64);
                uint o2 = __shfl_xor((int)k2, m, 64);
                uint n1 = k1 > o1 ? k1 : o1;
                uint lo = k1 > o1 ? o1 : k1;
                uint hi2 = k2 > o2 ? k2 : o2;
                k2 = lo > hi2 ? lo : hi2;
                k1 = n1;
            }
            if (li == 0) {
                const size_t base = ((size_t)(cbk * 64 + seg) * MROWS + row) * 2;
                cand[base] = k1; cand[base + 1] = k2;
            }
        }
    }
}

// ---------------------------------------------------------------------------
// K5: reduce. Per (row, cb): scan 64 segs x top-2 keys, take top-8, exact
// fp32 sequential dot (np-sgemm bits), d = fp32(Rn - 2M), min(d, idx).
// One wave per row-cb pair. Grid 8192, block 256.
// ---------------------------------------------------------------------------
__global__ __launch_bounds__(256) void k_reduce(const uint* __restrict__ cand,
                                                const float* __restrict__ h,
                                                const float* __restrict__ emb1,
                                                const float* __restrict__ emb2,
                                                const float* __restrict__ Rn,
                                                float* __restrict__ dout_idx) {
    const int tid = threadIdx.x;
    const int l = tid & 63, w = tid >> 6;
    const int item = blockIdx.x * 4 + w;
    const int cb  = item >> 14;
    const int row = item & (MROWS - 1);

    const size_t base = ((size_t)(cb * 64 + l) * MROWS + row) * 2;
    uint k1 = cand[base], k2 = cand[base + 1];

    uint mykey = 0;
    #pragma unroll
    for (int t = 0; t < 8; ++t) {
        uint m = k1 > k2 ? k1 : k2;
        #pragma unroll
        for (int off = 1; off < 64; off <<= 1) {
            uint o = __shfl_xor((int)m, off, 64);
            m = m > o ? m : o;
        }
        if (k1 == m) k1 = 0; else if (k2 == m) k2 = 0;
        if (l == t) mykey = m;
    }

    float dd = INFINITY; int code = 0x7fffffff;
    if (l < 8) {
        code = (int)(mykey & 0xFFFu);
        const float* hr = h + (size_t)row * TWO_D + cb * DD;
        const float* er = (cb ? emb2 : emb1) + (size_t)code * DD;
        float M = 0.f;
        for (int d = 0; d < DD; ++d) M = fmaf(hr[d], er[d], M);  // sequential chain
        dd = Rn[cb * MROWS + row] - 2.0f * M;
    }
    #pragma unroll
    for (int off = 1; off < 8; off <<= 1) {
        float od = __shfl_xor(dd, off, 64);
        int   oc = __shfl_xor(code, off, 64);
        if (od < dd || (od == dd && oc < code)) { dd = od; code = oc; }
    }
    if (l == 0) dout_idx[cb * MROWS + row] = (float)code;
}

// ---------------------------------------------------------------------------
// K6: per-row loss = (sum of both halves' squared diffs) * 0.625/256.
// Grid 16384, block 256.
// ---------------------------------------------------------------------------
__global__ __launch_bounds__(256) void k_loss(const float* __restrict__ h,
                                              const float* __restrict__ emb1,
                                              const float* __restrict__ emb2,
                                              const float* __restrict__ idxf,
                                              float* __restrict__ dout_loss) {
    __shared__ float red[4];
    const int r = blockIdx.x;
    const int d = threadIdx.x;
    const int ia = (int)idxf[r];
    const int ib = (int)idxf[MROWS + r];
    float e1 = emb1[(size_t)ia * DD + d];
    float e2 = emb2[(size_t)ib * DD + d];
    float h1 = h[(size_t)r * TWO_D + d];
    float h2 = h[(size_t)r * TWO_D + DD + d];
    float d1 = e1 - h1, d2 = e2 - h2;
    float p = d1 * d1 + d2 * d2;
    #pragma unroll
    for (int off = 32; off; off >>= 1) p += __shfl_down(p, off, 64);
    const int lane = d & 63, wv = d >> 6;
    if (lane == 0) red[wv] = p;
    __syncthreads();
    if (d == 0) {
        float s = red[0] + red[1] + red[2] + red[3];
        dout_loss[r] = s * (0.625f / 256.0f);
    }
}

// ---------------------------------------------------------------------------
// K7: out = gather(e_bf, idx) @ W_pq_bf + b_pq via MFMA (bf16 in, fp32 out).
// R5: same global_load_lds dbuf pipeline as K4 (source-side octet swizzle,
// gathered A rows are per-lane addresses -> legal for DMA). 16 k-chunks.
// Grid (128, 8), block 256.
// ---------------------------------------------------------------------------
__global__ __launch_bounds__(256) void k_gemm2m(const ushort* __restrict__ ebf,
                                                const ushort* __restrict__ wbfT,
                                                const float* __restrict__ idxf,
                                                const float* __restrict__ bpq,
                                                float* __restrict__ out) {
    __shared__ ushort Ab[2][4][128][8];   // 16 KB
    __shared__ ushort Bb[2][4][128][8];   // 16 KB
    const int tid = threadIdx.x;
    const int l = tid & 63, w = tid >> 6;
    const int rb    = blockIdx.x * 128;
    const int cbcol = blockIdx.y * 128;
    const int ry = (w & 1) * 64;
    const int cy = (w >> 1) * 64;
    const ushort* e1 = ebf;
    const ushort* e2 = ebf + (size_t)KC * DD;

    const int ia0 = (int)idxf[rb + l];
    const int ia1 = (int)idxf[rb + 64 + l];
    const int ib0 = (int)idxf[MROWS + rb + l];
    const int ib1 = (int)idxf[MROWS + rb + 64 + l];

    const int koct = (w ^ ((l >> 1) & 3)) * 8;
    const ushort* aA0 = e1 + (size_t)ia0 * DD + koct;   // half 0, rows it=0
    const ushort* aA1 = e1 + (size_t)ia1 * DD + koct;   // half 0, rows it=1
    const ushort* aB0 = e2 + (size_t)ib0 * DD + koct;   // half 1
    const ushort* aB1 = e2 + (size_t)ib1 * DD + koct;
    const ushort* bS0 = wbfT + (size_t)(cbcol + l) * TWO_D + koct;
    const ushort* bS1 = wbfT + (size_t)(cbcol + 64 + l) * TWO_D + koct;

#define GSTAGE(buf, c)                                                         \
    do {                                                                       \
        const int cbs_ = (c) >> 3;                                             \
        const int ka_  = ((c) * 32) & 255;                                     \
        GLD16(&Ab[buf][w][0][0],  (cbs_ ? aB0 : aA0) + ka_);                   \
        GLD16(&Ab[buf][w][64][0], (cbs_ ? aB1 : aA1) + ka_);                   \
        GLD16(&Bb[buf][w][0][0],  bS0 + (c) * 32);                             \
        GLD16(&Bb[buf][w][64][0], bS1 + (c) * 32);                             \
    } while (0)

    ffrag acc[4][4];
    #pragma unroll
    for (int i = 0; i < 4; ++i)
        #pragma unroll
        for (int j = 0; j < 4; ++j)
            acc[i][j] = (ffrag){0.f, 0.f, 0.f, 0.f};

    GSTAGE(0, 0);
    __syncthreads();

    const int q = l >> 4, li = l & 15;
    for (int c = 0; c < 16; ++c) {
        const int cur = c & 1;
        if (c < 15) GSTAGE(cur ^ 1, c + 1);   // async, drained by barrier
        bfrag afr[4], bfr[4];
        #pragma unroll
        for (int rf = 0; rf < 4; ++rf) {
            const int r = ry + rf * 16 + li;
            afr[rf] = *reinterpret_cast<const bfrag*>(&Ab[cur][q ^ ((r >> 1) & 3)][r][0]);
        }
        #pragma unroll
        for (int cf = 0; cf < 4; ++cf) {
            const int cc = cy + cf * 16 + li;
            bfr[cf] = *reinterpret_cast<const bfrag*>(&Bb[cur][q ^ ((cc >> 1) & 3)][cc][0]);
        }
        #pragma unroll
        for (int rf = 0; rf < 4; ++rf)
            #pragma unroll
            for (int cf = 0; cf < 4; ++cf)
                acc[rf][cf] = __builtin_amdgcn_mfma_f32_16x16x32_bf16(afr[rf], bfr[cf],
                                                                      acc[rf][cf], 0, 0, 0);
        __syncthreads();
    }
#undef GSTAGE

    #pragma unroll
    for (int rf = 0; rf < 4; ++rf) {
        #pragma unroll
        for (int reg = 0; reg < 4; ++reg) {
            const int row = rb + ry + rf * 16 + q * 4 + reg;
            #pragma unroll
            for (int cf = 0; cf < 4; ++cf) {
                const int col = cbcol + cy + cf * 16 + li;
                out[(size_t)row * OUTD + col] = acc[rf][cf][reg] + bpq[col];
            }
        }
    }
}

// ---------------------------------------------------------------------------
extern "C" void kernel_launch(void* const* d_in, const int* in_sizes, int n_in,
                              void* d_out, int out_size, void* d_ws, size_t ws_size,
                              hipStream_t stream) {
    const float* z    = (const float*)d_in[0];
    const float* Wqa  = (const float*)d_in[1];
    const float* bqa  = (const float*)d_in[2];
    const float* emb1 = (const float*)d_in[3];
    const float* emb2 = (const float*)d_in[4];
    const float* Wpq  = (const float*)d_in[5];
    const float* bpq  = (const float*)d_in[6];
    float* out = (float*)d_out;

    const size_t H = (size_t)MROWS * TWO_D;        // 8,388,608
    float*  hbuf = (float*)d_ws;                   // [H]            33.55 MB
    float*  Rn   = hbuf + H;                       // [2*MROWS]       0.13 MB
    ushort* hbf  = (ushort*)(Rn + 2 * MROWS);      // [H]            16.78 MB
    ushort* ebf  = hbf + H;                        // [2*KC*DD]       4.19 MB
    ushort* wbfT = ebf + 2 * (size_t)KC * DD;      // [OUTD*TWO_D]    1.05 MB
    uint*   cand = (uint*)(wbfT + (size_t)OUTD * TWO_D); // [2*64*MROWS*2] 16.78 MB

    float* dout_idx  = out + NZQ;
    float* dout_loss = out + NZQ + 2 * MROWS;

    k_gemm1<<<dim3(128, 4), 256, 0, stream>>>(z, Wqa, bqa, hbuf, hbf);
    k_rnorm<<<8192, 256, 0, stream>>>(hbuf, Rn);
    k_cvt<<<2560, 256, 0, stream>>>(emb1, emb2, Wpq, ebf, wbfT);
    k_score_mfma<<<dim3(128, 32, 2), 256, 0, stream>>>(hbf, ebf, cand);
    k_reduce<<<8192, 256, 0, stream>>>(cand, hbuf, emb1, emb2, Rn, dout_idx);
    k_loss<<<16384, 256, 0, stream>>>(hbuf, emb1, emb2, dout_idx, dout_loss);
    k_gemm2m<<<dim3(128, 8), 256, 0, stream>>>(ebf, wbfT, dout_idx, bpq, out);
}

// Round 6
// 543.097 us; speedup vs baseline: 1.4724x; 1.1381x over previous
//
#include <hip/hip_runtime.h>
#include <cstdint>
#include <cstddef>

#define MROWS 16384     // B*R = 32*512
#define INDIM 1024
#define DD    256
#define TWO_D 512
#define KC    4096
#define OUTD  1024
#define NZQ   (MROWS * OUTD)   // 16777216

typedef short bfrag __attribute__((ext_vector_type(8)));   // 8 bf16 (4 VGPRs)
typedef float ffrag __attribute__((ext_vector_type(4)));   // 4 fp32 acc

__device__ __forceinline__ ushort f2bf(float f) {          // RNE f32->bf16
    uint u = __float_as_uint(f);
    return (ushort)((u + 0x7FFFu + ((u >> 16) & 1u)) >> 16);
}

// async global->LDS, 16B per lane, dest = wave-uniform base + lane*16
#define GLD16(dst, src)                                                        \
    __builtin_amdgcn_global_load_lds(                                          \
        (const __attribute__((address_space(1))) unsigned int*)(src),          \
        (__attribute__((address_space(3))) unsigned int*)(dst), 16, 0, 0)

// ---------------------------------------------------------------------------
// K1: h = z @ W_qa + b_qa  (fp32, strict sequential-k accumulation -> matches
// np sgemm bits; LOAD-BEARING: per-element FMA chain must stay k-ascending).
// R3 structure (verified 225-228us): 128x128 tile, 8x8 microtile, 256 threads,
// global_load_lds dbuf staging, 1 barrier/step. Grid-limited to 2 blocks/CU;
// R4 showed smaller blocks lose occupancy. Grid (128, 4), block 256.
// ---------------------------------------------------------------------------
__global__ __launch_bounds__(256) void k_gemm1(const float* __restrict__ z,
                                               const float* __restrict__ Wqa,
                                               const float* __restrict__ bqa,
                                               float* __restrict__ h,
                                               ushort* __restrict__ hbf) {
    __shared__ float As[2][128][16];   // 16 KB  [buf][row][k] (k-quads swizzled)
    __shared__ float Bs[2][16][128];   // 16 KB  [buf][k][col] linear
    const int tid = threadIdx.x;
    const int l = tid & 63, w = tid >> 6;
    const int tx = tid & 15, ty = tid >> 4;
    const int rb = blockIdx.x * 128;
    const int cb = blockIdx.y * 128;

    float acc[8][8] = {};

    // --- staging source pointers (per lane) ---
    const int sA = 4 * ((l & 3) ^ ((l >> 4) & 3));
    const float* aA0 = z + (size_t)(rb + 32 * w + (l >> 2)) * INDIM + sA;
    const float* aA1 = aA0 + (size_t)16 * INDIM;
    const float* bB0 = Wqa + (size_t)(4 * w + (l >> 5)) * TWO_D + cb + (l & 31) * 4;
    const float* bB1 = bB0 + (size_t)2 * TWO_D;

#define STAGE(buf, k0)                                                         \
    do {                                                                       \
        GLD16(&As[buf][32 * w][0],      aA0 + (k0));                           \
        GLD16(&As[buf][32 * w + 16][0], aA1 + (k0));                           \
        GLD16(&Bs[buf][4 * w][0],       bB0 + (size_t)(k0) * TWO_D);           \
        GLD16(&Bs[buf][4 * w + 2][0],   bB1 + (size_t)(k0) * TWO_D);           \
    } while (0)

    STAGE(0, 0);
    __syncthreads();

    const int xk = ty & 3;    // read-side XOR key = (row>>2)&3 for all 8 rows
    for (int t = 0; t < 64; ++t) {
        const int cur = t & 1;
        if (t < 63) STAGE(cur ^ 1, (t + 1) * 16);   // async, lands by barrier
        #pragma unroll
        for (int q = 0; q < 4; ++q) {               // k-quad
            float fa[8][4];
            #pragma unroll
            for (int i = 0; i < 4; ++i) {
                *reinterpret_cast<float4*>(&fa[i][0]) =
                    *reinterpret_cast<const float4*>(&As[cur][ty * 4 + i][(q ^ xk) * 4]);
                *reinterpret_cast<float4*>(&fa[4 + i][0]) =
                    *reinterpret_cast<const float4*>(&As[cur][64 + ty * 4 + i][(q ^ xk) * 4]);
            }
            #pragma unroll
            for (int c = 0; c < 4; ++c) {           // kk = 4q+c, ascending
                const int kk = q * 4 + c;
                float4 b0 = *reinterpret_cast<const float4*>(&Bs[cur][kk][tx * 4]);
                float4 b1 = *reinterpret_cast<const float4*>(&Bs[cur][kk][64 + tx * 4]);
                float bv[8] = {b0.x, b0.y, b0.z, b0.w, b1.x, b1.y, b1.z, b1.w};
                #pragma unroll
                for (int i = 0; i < 8; ++i)
                    #pragma unroll
                    for (int j = 0; j < 8; ++j)
                        acc[i][j] = fmaf(fa[i][c], bv[j], acc[i][j]);
            }
        }
        __syncthreads();   // drains this wave's STAGE vmcnt + orders LDS reuse
    }
#undef STAGE

    #pragma unroll
    for (int i = 0; i < 8; ++i) {
        const int row = rb + ((i < 4) ? (ty * 4 + i) : (64 + ty * 4 + i - 4));
        #pragma unroll
        for (int jh = 0; jh < 2; ++jh) {
            const int col = cb + jh * 64 + tx * 4;
            float v0 = acc[i][jh * 4 + 0] + bqa[col + 0];
            float v1 = acc[i][jh * 4 + 1] + bqa[col + 1];
            float v2 = acc[i][jh * 4 + 2] + bqa[col + 2];
            float v3 = acc[i][jh * 4 + 3] + bqa[col + 3];
            float4 vf = {v0, v1, v2, v3};
            *reinterpret_cast<float4*>(&h[(size_t)row * TWO_D + col]) = vf;
            ushort u[4] = {f2bf(v0), f2bf(v1), f2bf(v2), f2bf(v3)};
            *reinterpret_cast<uint2*>(&hbf[(size_t)row * TWO_D + col]) =
                *reinterpret_cast<uint2*>(u);
        }
    }
}

// ---------------------------------------------------------------------------
// K2: row norms R[half][row] (fp32; few-ulp accuracy suffices — d = R-2M is
// exact on the quantum grid, so a uniform R shift preserves argmin & ties).
// Grid 8192, block 256.
// ---------------------------------------------------------------------------
__global__ __launch_bounds__(256) void k_rnorm(const float* __restrict__ h,
                                               float* __restrict__ Rn) {
    const int wave = threadIdx.x >> 6;
    const int lane = threadIdx.x & 63;
    const int item = blockIdx.x * 4 + wave;
    const int row  = item & (MROWS - 1);
    const int half = item >> 14;
    float4 v = *reinterpret_cast<const float4*>(&h[(size_t)row * TWO_D + half * DD + lane * 4]);
    float s = v.x * v.x + v.y * v.y + v.z * v.z + v.w * v.w;
    #pragma unroll
    for (int off = 32; off; off >>= 1) s += __shfl_down(s, off, 64);
    if (lane == 0) Rn[half * MROWS + row] = s;
}

// ---------------------------------------------------------------------------
// K3: fused bf16 converts. Blocks [0,2048): emb1|emb2 -> ebf.
// Blocks [2048,2560): W_pq [512][1024] -> transposed bf16 [1024][512].
// ---------------------------------------------------------------------------
__global__ __launch_bounds__(256) void k_cvt(const float* __restrict__ e1,
                                             const float* __restrict__ e2,
                                             const float* __restrict__ Wpq,
                                             ushort* __restrict__ ebf,
                                             ushort* __restrict__ wbfT) {
    const int b = blockIdx.x;
    if (b < 2048) {
        const size_t v = ((size_t)b * 256 + threadIdx.x) * 4;
        const size_t half = (size_t)KC * DD;
        const float* src = (v < half) ? (e1 + v) : (e2 + (v - half));
        float4 f = *reinterpret_cast<const float4*>(src);
        ebf[v + 0] = f2bf(f.x); ebf[v + 1] = f2bf(f.y);
        ebf[v + 2] = f2bf(f.z); ebf[v + 3] = f2bf(f.w);
    } else {
        const int e = ((b - 2048) * 256 + threadIdx.x) * 4;   // 0..524284
        const int k = e >> 10, c = e & 1023;
        float4 f = *reinterpret_cast<const float4*>(&Wpq[e]);
        wbfT[(size_t)(c + 0) * TWO_D + k] = f2bf(f.x);
        wbfT[(size_t)(c + 1) * TWO_D + k] = f2bf(f.y);
        wbfT[(size_t)(c + 2) * TWO_D + k] = f2bf(f.z);
        wbfT[(size_t)(c + 3) * TWO_D + k] = f2bf(f.w);
    }
}

// ---------------------------------------------------------------------------
// K4: MFMA score pass (selection only). C[row,code] = <h_bf, e_bf>, bf16
// 16x16x32 MFMA, 128x128 block tile, wave = 64x64 (4x4 frags), K=256 in 8
// chunks of 32. R5 structure: global_load_lds dbuf staging with source-side
// octet swizzle (verified). R6: cand layout now ITEM-MAJOR —
// cand[(cbk*MROWS+row)*128 + seg*2] — so k_reduce reads are contiguous.
// Per-wave per-row top-2 packed keys. Grid (128,32,2), block 256.
// ---------------------------------------------------------------------------
__global__ __launch_bounds__(256) void k_score_mfma(const ushort* __restrict__ hbf,
                                                    const ushort* __restrict__ ebf,
                                                    uint* __restrict__ cand) {
    __shared__ ushort Ab[2][4][128][8];   // 16 KB
    __shared__ ushort Bb[2][4][128][8];   // 16 KB
    const int tid = threadIdx.x;
    const int l = tid & 63, w = tid >> 6;
    const int rb    = blockIdx.x * 128;
    const int cbcol = blockIdx.y * 128;
    const int cbk   = blockIdx.z;
    const ushort* hb = hbf + cbk * DD;                 // row stride TWO_D
    const ushort* eb = ebf + (size_t)cbk * KC * DD;    // row stride DD

    const int ry = (w & 1) * 64;
    const int cy = (w >> 1) * 64;

    // staging: wave w writes subtile w linearly; lane l sources the octet
    // w ^ ((l>>1)&3) of its row -> Ab[s][r] = octet s ^ ((r>>1)&3) of row r.
    const int koct = (w ^ ((l >> 1) & 3)) * 8;
    const ushort* aS0 = hb + (size_t)(rb + l) * TWO_D + koct;
    const ushort* aS1 = hb + (size_t)(rb + 64 + l) * TWO_D + koct;
    const ushort* bS0 = eb + (size_t)(cbcol + l) * DD + koct;
    const ushort* bS1 = eb + (size_t)(cbcol + 64 + l) * DD + koct;

#define SSTAGE(buf, k0)                                                        \
    do {                                                                       \
        GLD16(&Ab[buf][w][0][0],  aS0 + (k0));                                 \
        GLD16(&Ab[buf][w][64][0], aS1 + (k0));                                 \
        GLD16(&Bb[buf][w][0][0],  bS0 + (k0));                                 \
        GLD16(&Bb[buf][w][64][0], bS1 + (k0));                                 \
    } while (0)

    ffrag acc[4][4];
    #pragma unroll
    for (int i = 0; i < 4; ++i)
        #pragma unroll
        for (int j = 0; j < 4; ++j)
            acc[i][j] = (ffrag){0.f, 0.f, 0.f, 0.f};

    SSTAGE(0, 0);
    __syncthreads();

    const int q = l >> 4, li = l & 15;
    for (int c = 0; c < 8; ++c) {
        const int cur = c & 1;
        if (c < 7) SSTAGE(cur ^ 1, (c + 1) * 32);   // async, drained by barrier
        bfrag afr[4], bfr[4];
        #pragma unroll
        for (int rf = 0; rf < 4; ++rf) {
            const int r = ry + rf * 16 + li;
            afr[rf] = *reinterpret_cast<const bfrag*>(&Ab[cur][q ^ ((r >> 1) & 3)][r][0]);
        }
        #pragma unroll
        for (int cf = 0; cf < 4; ++cf) {
            const int cc = cy + cf * 16 + li;
            bfr[cf] = *reinterpret_cast<const bfrag*>(&Bb[cur][q ^ ((cc >> 1) & 3)][cc][0]);
        }
        #pragma unroll
        for (int rf = 0; rf < 4; ++rf)
            #pragma unroll
            for (int cf = 0; cf < 4; ++cf)
                acc[rf][cf] = __builtin_amdgcn_mfma_f32_16x16x32_bf16(afr[rf], bfr[cf],
                                                                      acc[rf][cf], 0, 0, 0);
        __syncthreads();
    }
#undef SSTAGE

    const int seg = blockIdx.y * 2 + (w >> 1);
    #pragma unroll
    for (int rf = 0; rf < 4; ++rf) {
        #pragma unroll
        for (int reg = 0; reg < 4; ++reg) {
            const int row = rb + ry + rf * 16 + q * 4 + reg;
            uint k1 = 0, k2 = 0;
            #pragma unroll
            for (int cf = 0; cf < 4; ++cf) {
                float v = acc[rf][cf][reg];
                const int code = cbcol + cy + cf * 16 + li;
                uint u = __float_as_uint(v);
                u ^= (0x80000000u | (uint)((int)u >> 31));      // order-preserving flip
                const uint key = (u & 0xFFFFF000u) | (uint)code;
                if (key > k1) { k2 = k1; k1 = key; }
                else if (key > k2) { k2 = key; }
            }
            #pragma unroll
            for (int m = 1; m < 16; m <<= 1) {
                uint o1 = __shfl_xor((int)k1, m, 64);
                uint o2 = __shfl_xor((int)k2, m, 64);
                uint n1 = k1 > o1 ? k1 : o1;
                uint lo = k1 > o1 ? o1 : k1;
                uint hi2 = k2 > o2 ? k2 : o2;
                k2 = lo > hi2 ? lo : hi2;
                k1 = n1;
            }
            if (li == 0) {
                // item-major layout: 128 contiguous keys per (cbk,row)
                const size_t base = ((size_t)cbk * MROWS + row) * 128 + seg * 2;
                cand[base] = k1; cand[base + 1] = k2;
            }
        }
    }
}

// ---------------------------------------------------------------------------
// K5: reduce. R6 restructure: one wave = 8 items x 8 candidate lanes (was
// 1 wave/item with 8/64 lanes active). Per item: 128 contiguous keys, 16 per
// lane; top-8 extracted by 8 rounds of {local-max-16, 3-step 8-lane shfl max,
// remove} — identical top-8 SET as before (keys unique by code). Each lane
// then does ONE exact fp32 dot: float4 loads, fmaf in x,y,z,w order = same
// strictly-sequential d-ascending chain (bit-identical to scalar loop).
// d = fp32(Rn - 2M); 3-step (d,code)-lexicographic min over the 8 lanes.
// Grid 1024, block 256 (4 waves x 8 items = 32 items/block).
// ---------------------------------------------------------------------------
__global__ __launch_bounds__(256) void k_reduce(const uint* __restrict__ cand,
                                                const float* __restrict__ h,
                                                const float* __restrict__ emb1,
                                                const float* __restrict__ emb2,
                                                const float* __restrict__ Rn,
                                                float* __restrict__ dout_idx) {
    const int tid = threadIdx.x;
    const int l = tid & 63, w = tid >> 6;
    const int g = l & 7;                       // candidate slot within item
    const int item = blockIdx.x * 32 + w * 8 + (l >> 3);
    const int cb  = item >> 14;
    const int row = item & (MROWS - 1);

    // 16 contiguous keys per lane (8 lanes x 16 = this item's 128 keys)
    const uint* kp = cand + (size_t)item * 128 + g * 16;
    uint k[16];
    #pragma unroll
    for (int j = 0; j < 4; ++j) {
        uint4 v = *reinterpret_cast<const uint4*>(kp + j * 4);
        k[j * 4 + 0] = v.x; k[j * 4 + 1] = v.y;
        k[j * 4 + 2] = v.z; k[j * 4 + 3] = v.w;
    }

    uint mykey = 0;
    #pragma unroll
    for (int t = 0; t < 8; ++t) {
        uint m = k[0];
        #pragma unroll
        for (int j = 1; j < 16; ++j) m = k[j] > m ? k[j] : m;
        #pragma unroll
        for (int off = 1; off < 8; off <<= 1) {
            uint o = (uint)__shfl_xor((int)m, off, 64);
            m = o > m ? o : m;
        }
        #pragma unroll
        for (int j = 0; j < 16; ++j) k[j] = (k[j] == m) ? 0u : k[j];
        if (g == t) mykey = m;
    }

    const int code = (int)(mykey & 0xFFFu);
    const float* hr = h + (size_t)row * TWO_D + cb * DD;
    const float* er = (cb ? emb2 : emb1) + (size_t)code * DD;
    float M = 0.f;
    for (int d = 0; d < DD; d += 4) {        // sequential chain, vector loads
        float4 a = *reinterpret_cast<const float4*>(hr + d);
        float4 b = *reinterpret_cast<const float4*>(er + d);
        M = fmaf(a.x, b.x, M); M = fmaf(a.y, b.y, M);
        M = fmaf(a.z, b.z, M); M = fmaf(a.w, b.w, M);
    }
    float dd = Rn[cb * MROWS + row] - 2.0f * M;
    int c2 = code;
    #pragma unroll
    for (int off = 1; off < 8; off <<= 1) {
        float od = __shfl_xor(dd, off, 64);
        int   oc = __shfl_xor(c2, off, 64);
        if (od < dd || (od == dd && oc < c2)) { dd = od; c2 = oc; }
    }
    if (g == 0) dout_idx[cb * MROWS + row] = (float)c2;
}

// ---------------------------------------------------------------------------
// K6: per-row loss = (sum of both halves' squared diffs) * 0.625/256.
// Grid 16384, block 256.
// ---------------------------------------------------------------------------
__global__ __launch_bounds__(256) void k_loss(const float* __restrict__ h,
                                              const float* __restrict__ emb1,
                                              const float* __restrict__ emb2,
                                              const float* __restrict__ idxf,
                                              float* __restrict__ dout_loss) {
    __shared__ float red[4];
    const int r = blockIdx.x;
    const int d = threadIdx.x;
    const int ia = (int)idxf[r];
    const int ib = (int)idxf[MROWS + r];
    float e1 = emb1[(size_t)ia * DD + d];
    float e2 = emb2[(size_t)ib * DD + d];
    float h1 = h[(size_t)r * TWO_D + d];
    float h2 = h[(size_t)r * TWO_D + DD + d];
    float d1 = e1 - h1, d2 = e2 - h2;
    float p = d1 * d1 + d2 * d2;
    #pragma unroll
    for (int off = 32; off; off >>= 1) p += __shfl_down(p, off, 64);
    const int lane = d & 63, wv = d >> 6;
    if (lane == 0) red[wv] = p;
    __syncthreads();
    if (d == 0) {
        float s = red[0] + red[1] + red[2] + red[3];
        dout_loss[r] = s * (0.625f / 256.0f);
    }
}

// ---------------------------------------------------------------------------
// K7: out = gather(e_bf, idx) @ W_pq_bf + b_pq via MFMA (bf16 in, fp32 out).
// R5 structure: global_load_lds dbuf pipeline, source-side octet swizzle.
// Grid (128, 8), block 256.
// ---------------------------------------------------------------------------
__global__ __launch_bounds__(256) void k_gemm2m(const ushort* __restrict__ ebf,
                                                const ushort* __restrict__ wbfT,
                                                const float* __restrict__ idxf,
                                                const float* __restrict__ bpq,
                                                float* __restrict__ out) {
    __shared__ ushort Ab[2][4][128][8];   // 16 KB
    __shared__ ushort Bb[2][4][128][8];   // 16 KB
    const int tid = threadIdx.x;
    const int l = tid & 63, w = tid >> 6;
    const int rb    = blockIdx.x * 128;
    const int cbcol = blockIdx.y * 128;
    const int ry = (w & 1) * 64;
    const int cy = (w >> 1) * 64;
    const ushort* e1 = ebf;
    const ushort* e2 = ebf + (size_t)KC * DD;

    const int ia0 = (int)idxf[rb + l];
    const int ia1 = (int)idxf[rb + 64 + l];
    const int ib0 = (int)idxf[MROWS + rb + l];
    const int ib1 = (int)idxf[MROWS + rb + 64 + l];

    const int koct = (w ^ ((l >> 1) & 3)) * 8;
    const ushort* aA0 = e1 + (size_t)ia0 * DD + koct;   // half 0, rows it=0
    const ushort* aA1 = e1 + (size_t)ia1 * DD + koct;   // half 0, rows it=1
    const ushort* aB0 = e2 + (size_t)ib0 * DD + koct;   // half 1
    const ushort* aB1 = e2 + (size_t)ib1 * DD + koct;
    const ushort* bS0 = wbfT + (size_t)(cbcol + l) * TWO_D + koct;
    const ushort* bS1 = wbfT + (size_t)(cbcol + 64 + l) * TWO_D + koct;

#define GSTAGE(buf, c)                                                         \
    do {                                                                       \
        const int cbs_ = (c) >> 3;                                             \
        const int ka_  = ((c) * 32) & 255;                                     \
        GLD16(&Ab[buf][w][0][0],  (cbs_ ? aB0 : aA0) + ka_);                   \
        GLD16(&Ab[buf][w][64][0], (cbs_ ? aB1 : aA1) + ka_);                   \
        GLD16(&Bb[buf][w][0][0],  bS0 + (c) * 32);                             \
        GLD16(&Bb[buf][w][64][0], bS1 + (c) * 32);                             \
    } while (0)

    ffrag acc[4][4];
    #pragma unroll
    for (int i = 0; i < 4; ++i)
        #pragma unroll
        for (int j = 0; j < 4; ++j)
            acc[i][j] = (ffrag){0.f, 0.f, 0.f, 0.f};

    GSTAGE(0, 0);
    __syncthreads();

    const int q = l >> 4, li = l & 15;
    for (int c = 0; c < 16; ++c) {
        const int cur = c & 1;
        if (c < 15) GSTAGE(cur ^ 1, c + 1);   // async, drained by barrier
        bfrag afr[4], bfr[4];
        #pragma unroll
        for (int rf = 0; rf < 4; ++rf) {
            const int r = ry + rf * 16 + li;
            afr[rf] = *reinterpret_cast<const bfrag*>(&Ab[cur][q ^ ((r >> 1) & 3)][r][0]);
        }
        #pragma unroll
        for (int cf = 0; cf < 4; ++cf) {
            const int cc = cy + cf * 16 + li;
            bfr[cf] = *reinterpret_cast<const bfrag*>(&Bb[cur][q ^ ((cc >> 1) & 3)][cc][0]);
        }
        #pragma unroll
        for (int rf = 0; rf < 4; ++rf)
            #pragma unroll
            for (int cf = 0; cf < 4; ++cf)
                acc[rf][cf] = __builtin_amdgcn_mfma_f32_16x16x32_bf16(afr[rf], bfr[cf],
                                                                      acc[rf][cf], 0, 0, 0);
        __syncthreads();
    }
#undef GSTAGE

    #pragma unroll
    for (int rf = 0; rf < 4; ++rf) {
        #pragma unroll
        for (int reg = 0; reg < 4; ++reg) {
            const int row = rb + ry + rf * 16 + q * 4 + reg;
            #pragma unroll
            for (int cf = 0; cf < 4; ++cf) {
                const int col = cbcol + cy + cf * 16 + li;
                out[(size_t)row * OUTD + col] = acc[rf][cf][reg] + bpq[col];
            }
        }
    }
}

// ---------------------------------------------------------------------------
extern "C" void kernel_launch(void* const* d_in, const int* in_sizes, int n_in,
                              void* d_out, int out_size, void* d_ws, size_t ws_size,
                              hipStream_t stream) {
    const float* z    = (const float*)d_in[0];
    const float* Wqa  = (const float*)d_in[1];
    const float* bqa  = (const float*)d_in[2];
    const float* emb1 = (const float*)d_in[3];
    const float* emb2 = (const float*)d_in[4];
    const float* Wpq  = (const float*)d_in[5];
    const float* bpq  = (const float*)d_in[6];
    float* out = (float*)d_out;

    const size_t H = (size_t)MROWS * TWO_D;        // 8,388,608
    float*  hbuf = (float*)d_ws;                   // [H]            33.55 MB
    float*  Rn   = hbuf + H;                       // [2*MROWS]       0.13 MB
    ushort* hbf  = (ushort*)(Rn + 2 * MROWS);      // [H]            16.78 MB
    ushort* ebf  = hbf + H;                        // [2*KC*DD]       4.19 MB
    ushort* wbfT = ebf + 2 * (size_t)KC * DD;      // [OUTD*TWO_D]    1.05 MB
    uint*   cand = (uint*)(wbfT + (size_t)OUTD * TWO_D); // [2*MROWS*128]  16.78 MB

    float* dout_idx  = out + NZQ;
    float* dout_loss = out + NZQ + 2 * MROWS;

    k_gemm1<<<dim3(128, 4), 256, 0, stream>>>(z, Wqa, bqa, hbuf, hbf);
    k_rnorm<<<8192, 256, 0, stream>>>(hbuf, Rn);
    k_cvt<<<2560, 256, 0, stream>>>(emb1, emb2, Wpq, ebf, wbfT);
    k_score_mfma<<<dim3(128, 32, 2), 256, 0, stream>>>(hbf, ebf, cand);
    k_reduce<<<1024, 256, 0, stream>>>(cand, hbuf, emb1, emb2, Rn, dout_idx);
    k_loss<<<16384, 256, 0, stream>>>(hbuf, emb1, emb2, dout_idx, dout_loss);
    k_gemm2m<<<dim3(128, 8), 256, 0, stream>>>(ebf, wbfT, dout_idx, bpq, out);
}